// Round 3
// baseline (5219.996 us; speedup 1.0000x reference)
//
#include <hip/hip_runtime.h>

typedef float v2f __attribute__((ext_vector_type(2)));
typedef float v4f __attribute__((ext_vector_type(4)));

#define D_IN 14
#define HID  32
#define XT   16   // timesteps per xproj block

__device__ __forceinline__ float rcpf(float x) { return __builtin_amdgcn_rcpf(x); }

// Exchange with lane^32 partner via v_permlane32_swap_b32 (VALU-rate, no LDS).
// Correctness hardening vs round 2:
//  - b is produced by an opaque v_mov with early-clobber so a and b can NEVER
//    be register-coalesced into the same VGPR (same-reg swap is a lo<->hi
//    rotate, which silently corrupts the exchange).
//  - (a+b)-x is direction-proof: whichever halves the HW swaps, the pair
//    {a,b} per lane sums to x[l] + x[l^32], so (a+b)-x == partner (+<=1ulp).
__device__ __forceinline__ float xchg32(float x) {
    float a = x, b;
    asm("v_mov_b32 %0, %1" : "=&v"(b) : "v"(x));
    asm("v_permlane32_swap_b32 %0, %1" : "+v"(a), "+v"(b));
    return (a + b) - x;
}

// ---------------- phase 1: x projection (parallel) ----------------
// xp[m][t][r] = sum_d W_ih[m][r][d]*x[m][t0+t][d] + b_ih[m][r] + b_hh[m][r]
__global__ __launch_bounds__(128)
void xproj_kernel(const float* __restrict__ x,
                  const float* __restrict__ W_ih,
                  const float* __restrict__ b_ih,
                  const float* __restrict__ b_hh,
                  float* __restrict__ xp,
                  int t0, int cT, int T)
{
    const int m = blockIdx.y;
    const int r = threadIdx.x;            // gate row 0..127
    const int tlo = blockIdx.x * XT;

    v2f w[7];
    const v2f* wp = (const v2f*)(W_ih + (size_t)(m * 128 + r) * D_IN);
    #pragma unroll
    for (int q = 0; q < 7; ++q) w[q] = wp[q];
    const float bs = b_ih[m * 128 + r] + b_hh[m * 128 + r];

    #pragma unroll
    for (int tt = 0; tt < XT; ++tt) {
        int t = tlo + tt;
        if (t >= cT) break;
        const v2f* xr = (const v2f*)(x + ((size_t)m * T + t0 + t) * D_IN);
        v2f acc = {bs, 0.0f};
        #pragma unroll
        for (int q = 0; q < 7; ++q) acc = __builtin_elementwise_fma(w[q], xr[q], acc);
        xp[((size_t)m * cT + t) * 128 + r] = acc.x + acc.y;
    }
}

// ---------------- phase 2: sequential scan (1 block, 1 wave per LSTM) ----
// Lane l: gate rows rA=l (i|f), rB=l+64 (g|o); hi = l>>5; j = l&31.
__global__ __launch_bounds__(256, 1)
void lstm4_scan(const float* __restrict__ xp,
                const float* __restrict__ W_hh,
                float* __restrict__ carry,   // [0..127] h, [128..255] c
                float* __restrict__ out,
                const float* __restrict__ Wt,  const float* __restrict__ bt,
                const float* __restrict__ Wf1, const float* __restrict__ bf1,
                const float* __restrict__ Wf2, const float* __restrict__ bf2,
                int cT, int first, int last)
{
    __shared__ __align__(16) float hbuf[4][HID];
    __shared__ __align__(16) float dump[4][HID];   // write sink for lo lanes

    const int tid  = threadIdx.x;
    const int m    = tid >> 6;
    const int lane = tid & 63;
    const int hi   = lane >> 5;
    const int j    = lane & 31;
    const int rA   = lane;
    const int rB   = lane + 64;

    v2f wah[16], wbh[16];
    {
        const v2f* pA = (const v2f*)(W_hh + (size_t)(m * 128 + rA) * HID);
        const v2f* pB = (const v2f*)(W_hh + (size_t)(m * 128 + rB) * HID);
        #pragma unroll
        for (int q = 0; q < 16; ++q) { wah[q] = pA[q]; wbh[q] = pB[q]; }
    }

    const float* xb = xp + (size_t)m * cT * 128;

    // h-write destination: hi lanes own the canonical h slot, lo lanes hit a
    // dummy slot (2-way bank aliasing with the hi write = free). No exec-mask
    // divergence on the critical path.
    float* hdst = hi ? &hbuf[m][j] : &dump[m][j];

    float c;
    if (first) {
        if (lane < 32) hbuf[m][lane] = 0.0f;
        c = 0.0f;
    } else {
        if (lane < 32) hbuf[m][lane] = carry[m * 32 + lane];
        c = carry[128 + m * 32 + j];
    }
    asm volatile("" ::: "memory");   // init write visible before first read

    // ring-4 prefetch of the 2 per-lane gate x-projections
    float pa[4], pb[4];
    #pragma unroll
    for (int k = 0; k < 4; ++k) {
        int src = (k < cT) ? k : 0;
        pa[k] = xb[src * 128 + rA];
        pb[k] = xb[src * 128 + rB];
    }

#define STEP(XPA, XPB)                                                        \
    {                                                                         \
        v2f hv[16];                                                           \
        {                                                                     \
            const v4f* hp = (const v4f*)hbuf[m];                              \
            _Pragma("unroll")                                                 \
            for (int q = 0; q < 8; ++q) {                                     \
                v4f t4 = hp[q];                                               \
                v2f hlo = {t4.x, t4.y};                                       \
                v2f hhi = {t4.z, t4.w};                                       \
                hv[2 * q]     = hlo;                                          \
                hv[2 * q + 1] = hhi;                                          \
            }                                                                 \
        }                                                                     \
        v2f a0 = {XPA, 0.0f}, a1 = {0.0f, 0.0f};                              \
        v2f b0 = {XPB, 0.0f}, b1 = {0.0f, 0.0f};                              \
        _Pragma("unroll")                                                     \
        for (int q = 0; q < 16; q += 2) {                                     \
            a0 = __builtin_elementwise_fma(wah[q],     hv[q],     a0);        \
            a1 = __builtin_elementwise_fma(wah[q + 1], hv[q + 1], a1);        \
            b0 = __builtin_elementwise_fma(wbh[q],     hv[q],     b0);        \
            b1 = __builtin_elementwise_fma(wbh[q + 1], hv[q + 1], b1);        \
        }                                                                     \
        v2f asum = a0 + a1, bsum = b0 + b1;                                   \
        float accA = asum.x + asum.y;                                         \
        float accB = bsum.x + bsum.y;                                         \
        float actA = rcpf(1.0f + __expf(-accA));          /* sig(i) | sig(f) */\
        float eB   = __expf(hi ? -accB : 2.0f * accB);                        \
        float rBv  = rcpf(1.0f + eB);                                         \
        float actB = hi ? rBv : 1.0f - 2.0f * rBv;        /* tanh(g)|sig(o) */\
        float x0   = hi ? actA : actA * actB;             /* sig(f) | u     */\
        float y0   = xchg32(x0);                          /* u | sig(f)     */\
        float sf   = hi ? actA : y0;                                         \
        float u    = hi ? y0   : x0;                                         \
        c = __builtin_fmaf(sf, c, u);                                        \
        float tc = 1.0f - 2.0f * rcpf(1.0f + __expf(2.0f * c));              \
        *hdst = actB * tc;   /* hi lanes: sig(o)*tanh(c); lo lanes: sink */  \
        asm volatile("" ::: "memory");  /* order write before next read */   \
    }

    int t = 0;
    for (; t + 4 <= cT; t += 4) {
        STEP(pa[0], pb[0])
        { int tn = t + 4; int src = (tn < cT) ? tn : 0;
          pa[0] = xb[src * 128 + rA]; pb[0] = xb[src * 128 + rB]; }
        STEP(pa[1], pb[1])
        { int tn = t + 5; int src = (tn < cT) ? tn : 0;
          pa[1] = xb[src * 128 + rA]; pb[1] = xb[src * 128 + rB]; }
        STEP(pa[2], pb[2])
        { int tn = t + 6; int src = (tn < cT) ? tn : 0;
          pa[2] = xb[src * 128 + rA]; pb[2] = xb[src * 128 + rB]; }
        STEP(pa[3], pb[3])
        { int tn = t + 7; int src = (tn < cT) ? tn : 0;
          pa[3] = xb[src * 128 + rA]; pb[3] = xb[src * 128 + rB]; }
    }
    for (; t < cT; ++t) {   // tail (only when cT not multiple of 4)
        float qa = xb[t * 128 + rA], qb = xb[t * 128 + rB];
        STEP(qa, qb)
    }
#undef STEP

    // carry out h,c (canonical values live in hi lanes / LDS)
    if (hi) {
        carry[128 + m * 32 + j] = c;
        carry[m * 32 + j]       = hbuf[m][j];
    }

    __syncthreads();

    if (last) {
        if (tid == 0) {
            float s = bt[0];
            const float* hf = &hbuf[0][0];
            #pragma unroll
            for (int k = 0; k < 128; ++k) s += hf[k] * Wt[k];
            out[0] = s;
        } else if (tid == 1) {
            float s = bf1[0];
            #pragma unroll
            for (int k = 0; k < 32; ++k) s += hbuf[1][k] * Wf1[k];
            out[1] = s;
        } else if (tid == 2) {
            float s = bf2[0];
            #pragma unroll
            for (int k = 0; k < 32; ++k) s += hbuf[2][k] * Wf2[k];
            out[2] = s;
        } else if (tid == 3) {
            float s = bf2[0];
            #pragma unroll
            for (int k = 0; k < 32; ++k) s += hbuf[3][k] * Wf2[k];
            out[3] = s;
        }
    }
}

extern "C" void kernel_launch(void* const* d_in, const int* in_sizes, int n_in,
                              void* d_out, int out_size, void* d_ws, size_t ws_size,
                              hipStream_t stream) {
    const float* x    = (const float*)d_in[0];
    const float* W_ih = (const float*)d_in[1];
    const float* W_hh = (const float*)d_in[2];
    const float* b_ih = (const float*)d_in[3];
    const float* b_hh = (const float*)d_in[4];
    const float* Wt   = (const float*)d_in[5];
    const float* bt   = (const float*)d_in[6];
    const float* Wf1  = (const float*)d_in[7];
    const float* bf1  = (const float*)d_in[8];
    const float* Wf2  = (const float*)d_in[9];
    const float* bf2  = (const float*)d_in[10];

    const int T = in_sizes[0] / (4 * D_IN);   // 16384

    float* carry = (float*)d_ws;                       // 256 floats
    float* xpbuf = (float*)((char*)d_ws + 1024);
    size_t avail = (ws_size > 1024) ? ws_size - 1024 : 0;

    // steps of xproj that fit: 4 LSTMs * 128 rows * 4B = 2048 B per step
    long cmax = (long)(avail / 2048);
    cmax = (cmax / 4) * 4;
    if (cmax > T) cmax = T;
    if (cmax < 4) cmax = 4;                            // assume ws >= ~10 KB

    int nch = (T + (int)cmax - 1) / (int)cmax;
    int cT0 = (T + nch - 1) / nch;
    cT0 = ((cT0 + 3) / 4) * 4;
    if (cT0 > (int)cmax) cT0 = (int)cmax;

    int done = 0;
    while (done < T) {
        int cT = (T - done < cT0) ? (T - done) : cT0;
        dim3 gx((cT + XT - 1) / XT, 4);
        xproj_kernel<<<gx, 128, 0, stream>>>(x, W_ih, b_ih, b_hh, xpbuf,
                                             done, cT, T);
        lstm4_scan<<<1, 256, 0, stream>>>(xpbuf, W_hh, carry, (float*)d_out,
                                          Wt, bt, Wf1, bf1, Wf2, bf2,
                                          cT, done == 0 ? 1 : 0,
                                          (done + cT >= T) ? 1 : 0);
        done += cT;
    }
}

// Round 4
// 5136.470 us; speedup vs baseline: 1.0163x; 1.0163x over previous
//
#include <hip/hip_runtime.h>

typedef float v2f __attribute__((ext_vector_type(2)));

#define D_IN 14
#define HID  32

__device__ __forceinline__ float rcpf(float x) { return __builtin_amdgcn_rcpf(x); }

// Exchange with lane^32 partner via v_permlane32_swap_b32 (VALU-rate, no LDS).
//  - b produced by opaque v_mov with early-clobber: a,b can never be
//    register-coalesced into the same VGPR (same-reg swap corrupts).
//  - (a+b)-x is direction-proof: under either half-swap semantic the pair
//    {a,b} sums per-lane to x[l] + x[l^32], so (a+b)-x == partner (+<=1ulp).
// Proven bit-adequate in round 3 (absmax 0.0).
__device__ __forceinline__ float xchg32(float x) {
    float a = x, b;
    asm("v_mov_b32 %0, %1" : "=&v"(b) : "v"(x));
    asm("v_permlane32_swap_b32 %0, %1" : "+v"(a), "+v"(b));
    return (a + b) - x;
}

__device__ __forceinline__ float lane_bcast(float v, int srclane) {
    return __int_as_float(__builtin_amdgcn_readlane(__float_as_int(v), srclane));
}

// 4 independent LSTMs, one wave each, single 256-thread block, ONE launch.
// Lane l: gate rows rA=l (i|f), rB=l+64 (g|o); hi=l>>5; j=l&31.
// h lives as 32 wave-uniform floats (SGPRs), refreshed each step by 32
// v_readlane from the hi half (lane 32+j holds h[j]). No LDS in the loop.
__global__ __launch_bounds__(256, 1)
void lstm4_scan(const float* __restrict__ x,
                const float* __restrict__ W_ih,
                const float* __restrict__ W_hh,
                const float* __restrict__ b_ih,
                const float* __restrict__ b_hh,
                const float* __restrict__ Wt,  const float* __restrict__ bt,
                const float* __restrict__ Wf1, const float* __restrict__ bf1,
                const float* __restrict__ Wf2, const float* __restrict__ bf2,
                float* __restrict__ out,
                int T)
{
    __shared__ __align__(16) float hbuf[4][HID];

    const int tid  = threadIdx.x;
    const int m    = tid >> 6;
    const int lane = tid & 63;
    const int hi   = lane >> 5;
    const int j    = lane & 31;
    const int rA   = lane;
    const int rB   = lane + 64;

    // ---- persistent weights in VGPRs ----
    v2f wah[16], wbh[16];
    {
        const v2f* pA = (const v2f*)(W_hh + (size_t)(m * 128 + rA) * HID);
        const v2f* pB = (const v2f*)(W_hh + (size_t)(m * 128 + rB) * HID);
        #pragma unroll
        for (int q = 0; q < 16; ++q) { wah[q] = pA[q]; wbh[q] = pB[q]; }
    }
    v2f wax[7], wbx[7];
    {
        const v2f* pA = (const v2f*)(W_ih + (size_t)(m * 128 + rA) * D_IN);
        const v2f* pB = (const v2f*)(W_ih + (size_t)(m * 128 + rB) * D_IN);
        #pragma unroll
        for (int q = 0; q < 7; ++q) { wax[q] = pA[q]; wbx[q] = pB[q]; }
    }
    const float bA = b_ih[m * 128 + rA] + b_hh[m * 128 + rA];
    const float bB = b_ih[m * 128 + rB] + b_hh[m * 128 + rB];

    // x stream (wave-uniform address -> scalar-cached loads)
    const v2f* xs = (const v2f*)(x + (size_t)m * T * D_IN);
    v2f xb0[7], xb1[7];
    #pragma unroll
    for (int q = 0; q < 7; ++q) { xb0[q] = xs[q]; xb1[q] = xs[7 + q]; }

    // ---- state: h uniform (SGPRs), c per-lane (replicated in pair) ----
    float hs[HID];
    #pragma unroll
    for (int k = 0; k < HID; ++k) hs[k] = 0.0f;
    float c = 0.0f;
    float vh = 0.0f;   // last-written per-lane h (hi lanes canonical)

#define STEP(t, xb)                                                            \
    {                                                                          \
        /* x-part (off-chain) */                                               \
        v2f av = {bA, 0.0f}, bv = {bB, 0.0f};                                  \
        _Pragma("unroll")                                                      \
        for (int q = 0; q < 7; ++q) {                                          \
            av = __builtin_elementwise_fma(wax[q], xb[q], av);                 \
            bv = __builtin_elementwise_fma(wbx[q], xb[q], bv);                 \
        }                                                                      \
        if ((t) + 2 < T) {                                                     \
            const v2f* p = xs + (size_t)((t) + 2) * 7;                         \
            _Pragma("unroll")                                                  \
            for (int q = 0; q < 7; ++q) xb[q] = p[q];                          \
        }                                                                      \
        /* h-part: uniform h (SGPR) x VGPR weights, 4 independent chains */    \
        v2f a0 = av, a1 = {0.0f, 0.0f};                                        \
        v2f b0 = bv, b1 = {0.0f, 0.0f};                                        \
        _Pragma("unroll")                                                      \
        for (int q = 0; q < 16; q += 2) {                                      \
            v2f h0; h0.x = hs[2 * q];     h0.y = hs[2 * q + 1];                \
            v2f h1; h1.x = hs[2 * q + 2]; h1.y = hs[2 * q + 3];                \
            a0 = __builtin_elementwise_fma(wah[q],     h0, a0);                \
            a1 = __builtin_elementwise_fma(wah[q + 1], h1, a1);                \
            b0 = __builtin_elementwise_fma(wbh[q],     h0, b0);                \
            b1 = __builtin_elementwise_fma(wbh[q + 1], h1, b1);                \
        }                                                                      \
        v2f asum = a0 + a1, bsum = b0 + b1;                                    \
        float accA = asum.x + asum.y;                                          \
        float accB = bsum.x + bsum.y;                                          \
        float actA = rcpf(1.0f + __expf(-accA));          /* sig(i)|sig(f) */  \
        float eB   = __expf(hi ? -accB : 2.0f * accB);                         \
        float rBv  = rcpf(1.0f + eB);                                          \
        float actB = hi ? rBv : 1.0f - 2.0f * rBv;        /* tanh(g)|sig(o) */ \
        float x0   = hi ? actA : actA * actB;             /* sig(f) | u */     \
        float y0   = xchg32(x0);                          /* u | sig(f) */     \
        float sf   = hi ? actA : y0;                                           \
        float u    = hi ? y0   : x0;                                           \
        c = __builtin_fmaf(sf, c, u);                                          \
        float tc = 1.0f - 2.0f * rcpf(1.0f + __expf(2.0f * c));                \
        vh = actB * tc;                 /* hi lanes: h[j]; lo lanes: junk */   \
        _Pragma("unroll")                                                      \
        for (int k = 0; k < HID; ++k) hs[k] = lane_bcast(vh, 32 + k);          \
    }

    for (int t = 0; t < T; t += 2) {
        STEP(t, xb0)
        STEP(t + 1, xb1)
    }
#undef STEP

    // publish final h (hi lanes hold canonical per-lane copy)
    if (hi) hbuf[m][j] = vh;
    __syncthreads();

    // ---- heads (return order: target, f1, f2, f3; f3 reuses Wf2/bf2) ----
    if (tid == 0) {
        float s = bt[0];
        const float* hf = &hbuf[0][0];
        #pragma unroll
        for (int k = 0; k < 128; ++k) s += hf[k] * Wt[k];
        out[0] = s;
    } else if (tid == 1) {
        float s = bf1[0];
        #pragma unroll
        for (int k = 0; k < 32; ++k) s += hbuf[1][k] * Wf1[k];
        out[1] = s;
    } else if (tid == 2) {
        float s = bf2[0];
        #pragma unroll
        for (int k = 0; k < 32; ++k) s += hbuf[2][k] * Wf2[k];
        out[2] = s;
    } else if (tid == 3) {
        float s = bf2[0];
        #pragma unroll
        for (int k = 0; k < 32; ++k) s += hbuf[3][k] * Wf2[k];
        out[3] = s;
    }
}

extern "C" void kernel_launch(void* const* d_in, const int* in_sizes, int n_in,
                              void* d_out, int out_size, void* d_ws, size_t ws_size,
                              hipStream_t stream) {
    const float* x    = (const float*)d_in[0];
    const float* W_ih = (const float*)d_in[1];
    const float* W_hh = (const float*)d_in[2];
    const float* b_ih = (const float*)d_in[3];
    const float* b_hh = (const float*)d_in[4];
    const float* Wt   = (const float*)d_in[5];
    const float* bt   = (const float*)d_in[6];
    const float* Wf1  = (const float*)d_in[7];
    const float* bf1  = (const float*)d_in[8];
    const float* Wf2  = (const float*)d_in[9];
    const float* bf2  = (const float*)d_in[10];

    const int T = in_sizes[0] / (4 * D_IN);   // 16384

    lstm4_scan<<<1, 256, 0, stream>>>(x, W_ih, W_hh, b_ih, b_hh,
                                      Wt, bt, Wf1, bf1, Wf2, bf2,
                                      (float*)d_out, T);
}

// Round 5
// 4785.861 us; speedup vs baseline: 1.0907x; 1.0733x over previous
//
#include <hip/hip_runtime.h>

typedef float v2f __attribute__((ext_vector_type(2)));
typedef float v4f __attribute__((ext_vector_type(4)));

#define D_IN 14
#define HID  32

#define LOG2E      1.4426950408889634f
#define TWO_LOG2E  2.8853900817779268f

__device__ __forceinline__ float rcpf(float x) { return __builtin_amdgcn_rcpf(x); }

#if __has_builtin(__builtin_amdgcn_exp2f)
__device__ __forceinline__ float exp2ff(float x) { return __builtin_amdgcn_exp2f(x); }
#else
__device__ __forceinline__ float exp2ff(float x) { return exp2f(x); }
#endif

// Exchange with lane^32 partner via v_permlane32_swap_b32 (proven in round 3).
__device__ __forceinline__ float xchg32(float x) {
    float a = x, b;
    asm("v_mov_b32 %0, %1" : "=&v"(b) : "v"(x));
    asm("v_permlane32_swap_b32 %0, %1" : "+v"(a), "+v"(b));
    return (a + b) - x;
}

// One LSTM per block (blockIdx.x = m), one wave of 64 lanes, private CU.
// Lane l: gate rows rA=l (i|f), rB=l+64 (g|o); hi=l>>5; j=l&31.
// Weights prescaled so every activation is rcp(1 + exp2(acc)):
//   rows A (i|f, sigmoid):      scale -log2e,  sig = r
//   rows B lo (g, tanh):        scale 2*log2e, tanh = 1-2r
//   rows B hi (o, sigmoid):     scale -log2e,  sig = r
__global__ __launch_bounds__(64, 1)
void lstm_scan_m(const float* __restrict__ x,
                 const float* __restrict__ W_ih,
                 const float* __restrict__ W_hh,
                 const float* __restrict__ b_ih,
                 const float* __restrict__ b_hh,
                 const float* __restrict__ Wt,  const float* __restrict__ bt,
                 const float* __restrict__ Wf1, const float* __restrict__ bf1,
                 const float* __restrict__ Wf2, const float* __restrict__ bf2,
                 float* __restrict__ hws,        // [128] final h, m-major
                 unsigned* __restrict__ flag,    // arrival counter (zeroed per call)
                 float* __restrict__ out,
                 int T)
{
    __shared__ __align__(16) float hbuf[HID];
    __shared__ __align__(16) float dump[HID];   // write sink for lo lanes

    const int m    = blockIdx.x;
    const int lane = threadIdx.x;      // 0..63
    const int hi   = lane >> 5;
    const int j    = lane & 31;
    const int rA   = lane;
    const int rB   = lane + 64;

    const float sA = -LOG2E;
    const float sB = hi ? -LOG2E : TWO_LOG2E;

    // ---- persistent prescaled weights in VGPRs ----
    v2f wah[16], wbh[16];
    {
        const v2f* pA = (const v2f*)(W_hh + (size_t)(m * 128 + rA) * HID);
        const v2f* pB = (const v2f*)(W_hh + (size_t)(m * 128 + rB) * HID);
        #pragma unroll
        for (int q = 0; q < 16; ++q) {
            v2f a = pA[q], b = pB[q];
            a.x *= sA; a.y *= sA; b.x *= sB; b.y *= sB;
            wah[q] = a; wbh[q] = b;
        }
    }
    v2f wax[7], wbx[7];
    {
        const v2f* pA = (const v2f*)(W_ih + (size_t)(m * 128 + rA) * D_IN);
        const v2f* pB = (const v2f*)(W_ih + (size_t)(m * 128 + rB) * D_IN);
        #pragma unroll
        for (int q = 0; q < 7; ++q) {
            v2f a = pA[q], b = pB[q];
            a.x *= sA; a.y *= sA; b.x *= sB; b.y *= sB;
            wax[q] = a; wbx[q] = b;
        }
    }
    const float bA = (b_ih[m * 128 + rA] + b_hh[m * 128 + rA]) * sA;
    const float bB = (b_ih[m * 128 + rB] + b_hh[m * 128 + rB]) * sB;

    // x stream (wave-uniform address), ring-2 prefetch
    const v2f* xs = (const v2f*)(x + (size_t)m * T * D_IN);
    v2f xb0[7], xb1[7];
    #pragma unroll
    for (int q = 0; q < 7; ++q) { xb0[q] = xs[q]; xb1[q] = xs[7 + q]; }

    // h-write destination: hi lanes own hbuf[j], lo lanes hit dump[j]
    float* hdst = hi ? &hbuf[j] : &dump[j];

    if (lane < 32) hbuf[lane] = 0.0f;
    float c = 0.0f;
    float vh = 0.0f;
    asm volatile("" ::: "memory");

#define STEP(t, xb)                                                            \
    {                                                                          \
        /* x-part (off-chain) */                                               \
        v2f av = {bA, 0.0f}, bv = {bB, 0.0f};                                  \
        _Pragma("unroll")                                                      \
        for (int q = 0; q < 7; ++q) {                                          \
            av = __builtin_elementwise_fma(wax[q], xb[q], av);                 \
            bv = __builtin_elementwise_fma(wbx[q], xb[q], bv);                 \
        }                                                                      \
        { /* branch-free clamped prefetch for t+2 */                           \
            int tn = (t) + 2; tn = (tn < T) ? tn : (T - 1);                    \
            const v2f* p = xs + (size_t)tn * 7;                                \
            _Pragma("unroll")                                                  \
            for (int q = 0; q < 7; ++q) xb[q] = p[q];                          \
        }                                                                      \
        /* h broadcast from LDS: 8x ds_read_b128 */                            \
        v2f hv[16];                                                            \
        {                                                                      \
            const v4f* hp = (const v4f*)hbuf;                                  \
            _Pragma("unroll")                                                  \
            for (int q = 0; q < 8; ++q) {                                      \
                v4f t4 = hp[q];                                                \
                v2f hlo = {t4.x, t4.y};                                        \
                v2f hhi = {t4.z, t4.w};                                        \
                hv[2 * q]     = hlo;                                           \
                hv[2 * q + 1] = hhi;                                           \
            }                                                                  \
        }                                                                      \
        /* 8 independent depth-4 pk-FMA chains */                              \
        v2f a0 = av, a1 = {0.0f, 0.0f}, a2 = {0.0f, 0.0f}, a3 = {0.0f, 0.0f}; \
        v2f b0 = bv, b1 = {0.0f, 0.0f}, b2 = {0.0f, 0.0f}, b3 = {0.0f, 0.0f}; \
        _Pragma("unroll")                                                      \
        for (int q = 0; q < 16; q += 4) {                                      \
            a0 = __builtin_elementwise_fma(wah[q],     hv[q],     a0);         \
            a1 = __builtin_elementwise_fma(wah[q + 1], hv[q + 1], a1);         \
            a2 = __builtin_elementwise_fma(wah[q + 2], hv[q + 2], a2);         \
            a3 = __builtin_elementwise_fma(wah[q + 3], hv[q + 3], a3);         \
            b0 = __builtin_elementwise_fma(wbh[q],     hv[q],     b0);         \
            b1 = __builtin_elementwise_fma(wbh[q + 1], hv[q + 1], b1);         \
            b2 = __builtin_elementwise_fma(wbh[q + 2], hv[q + 2], b2);         \
            b3 = __builtin_elementwise_fma(wbh[q + 3], hv[q + 3], b3);         \
        }                                                                      \
        v2f as_ = (a0 + a1) + (a2 + a3);                                       \
        v2f bs_ = (b0 + b1) + (b2 + b3);                                       \
        float accA = as_.x + as_.y;                                            \
        float accB = bs_.x + bs_.y;                                            \
        /* activations via exp2 on prescaled accs */                           \
        float actA = rcpf(1.0f + exp2ff(accA));           /* sig(i)|sig(f) */  \
        float rBv  = rcpf(1.0f + exp2ff(accB));                                \
        float actB = hi ? rBv : __builtin_fmaf(-2.0f, rBv, 1.0f);              \
        float x0   = hi ? actA : actA * actB;             /* sig(f) | u */     \
        float y0   = xchg32(x0);                          /* u | sig(f) */     \
        float sf   = hi ? actA : y0;                                           \
        float u    = hi ? y0   : x0;                                           \
        c = __builtin_fmaf(sf, c, u);                                          \
        float r2 = rcpf(1.0f + exp2ff(c * TWO_LOG2E));                         \
        float tc = __builtin_fmaf(-2.0f, r2, 1.0f);                            \
        vh = actB * tc;               /* hi: sig(o)*tanh(c); lo: junk */       \
        *hdst = vh;                                                            \
        asm volatile("" ::: "memory");                                         \
    }

    for (int t = 0; t < T; t += 2) {
        STEP(t, xb0)
        STEP(t + 1, xb1)
    }
#undef STEP

    // publish final h to workspace (hi lanes canonical)
    if (hi) hws[m * 32 + j] = vh;
    __threadfence();                      // device-scope release

    if (lane == 0) {
        unsigned old = atomicAdd(flag, 1u);   // device-scope
        if (old == 3u) {                      // last block computes all heads
            __threadfence();                  // acquire
            float s0 = bt[0];
            #pragma unroll
            for (int k = 0; k < 128; ++k) s0 += hws[k] * Wt[k];
            out[0] = s0;
            float s1 = bf1[0];
            #pragma unroll
            for (int k = 0; k < 32; ++k) s1 += hws[32 + k] * Wf1[k];
            out[1] = s1;
            float s2 = bf2[0];
            #pragma unroll
            for (int k = 0; k < 32; ++k) s2 += hws[64 + k] * Wf2[k];
            out[2] = s2;
            float s3 = bf2[0];
            #pragma unroll
            for (int k = 0; k < 32; ++k) s3 += hws[96 + k] * Wf2[k];
            out[3] = s3;
        }
    }
}

extern "C" void kernel_launch(void* const* d_in, const int* in_sizes, int n_in,
                              void* d_out, int out_size, void* d_ws, size_t ws_size,
                              hipStream_t stream) {
    const float* x    = (const float*)d_in[0];
    const float* W_ih = (const float*)d_in[1];
    const float* W_hh = (const float*)d_in[2];
    const float* b_ih = (const float*)d_in[3];
    const float* b_hh = (const float*)d_in[4];
    const float* Wt   = (const float*)d_in[5];
    const float* bt   = (const float*)d_in[6];
    const float* Wf1  = (const float*)d_in[7];
    const float* bf1  = (const float*)d_in[8];
    const float* Wf2  = (const float*)d_in[9];
    const float* bf2  = (const float*)d_in[10];

    const int T = in_sizes[0] / (4 * D_IN);   // 16384

    unsigned* flag = (unsigned*)d_ws;                 // 4 B counter
    float*    hws  = (float*)((char*)d_ws + 256);     // 128 floats

    hipMemsetAsync(d_ws, 0, 256, stream);             // zero flag each call

    lstm_scan_m<<<4, 64, 0, stream>>>(x, W_ih, W_hh, b_ih, b_hh,
                                      Wt, bt, Wf1, bf1, Wf2, bf2,
                                      hws, flag, (float*)d_out, T);
}